// Round 1
// baseline (1051.574 us; speedup 1.0000x reference)
//
#include <hip/hip_runtime.h>
#include <hip/hip_bf16.h>
#include <stdint.h>

#define DIM   1024
#define NSEQ  4096
#define NBAT  4
#define NH    16
#define HD    64
#define MROWS (NBAT*NSEQ)   // 16384

typedef __attribute__((ext_vector_type(8))) short  short8;
typedef __attribute__((ext_vector_type(4))) float  f32x4;
typedef __attribute__((ext_vector_type(4))) unsigned int  u32x4;
typedef __attribute__((ext_vector_type(4))) unsigned short u16x4;

// ---- helpers -------------------------------------------------------------
__device__ inline unsigned short bf16_rne(float x) {
    unsigned u = __builtin_bit_cast(unsigned, x);
    u += 0x7FFFu + ((u >> 16) & 1u);
    return (unsigned short)(u >> 16);
}
__device__ inline float bf16_to_f32(unsigned short h) {
    return __builtin_bit_cast(float, ((unsigned)h) << 16);
}
// pack two f32 -> two bf16 in one dword (round-half-away via +0x8000, then v_perm)
__device__ inline unsigned pack2_rh(float a, float b) {
    unsigned ua = __builtin_bit_cast(unsigned, a) + 0x8000u;
    unsigned ub = __builtin_bit_cast(unsigned, b) + 0x8000u;
    // result bytes: [ua.b2, ua.b3, ub.b2, ub.b3]  (a -> low 16, b -> high 16)
    return __builtin_amdgcn_perm(ub, ua, 0x07060302u);
}

// ---- fp32 -> bf16 convert (weights) --------------------------------------
__global__ __launch_bounds__(256) void cvt_kernel(const float* __restrict__ src,
                                                  unsigned short* __restrict__ dst,
                                                  int n4) {
    int i = blockIdx.x * blockDim.x + threadIdx.x;
    if (i >= n4) return;
    f32x4 v = ((const f32x4*)src)[i];
    u16x4 o;
    o[0] = bf16_rne(v[0]); o[1] = bf16_rne(v[1]);
    o[2] = bf16_rne(v[2]); o[3] = bf16_rne(v[3]);
    ((u16x4*)dst)[i] = o;
}

// ---- main GEMM: C[M,DIM] = act(A[M,DIM] @ W[DIM,DIM]^T + bias) -----------
// ACT: 0 = none, 1 = relu, 2 = relu + zero masked rows
// AF32: A is fp32 (convert inline), else bf16
// OUTF32: store fp32, else bf16
template<int ACT, bool AF32, bool OUTF32>
__global__ __launch_bounds__(256) void gemm_kernel(const void* __restrict__ Ap,
                                                   const unsigned short* __restrict__ Wb,
                                                   const float* __restrict__ bias,
                                                   void* __restrict__ Cp,
                                                   const int* __restrict__ mask) {
    const int mb   = blockIdx.x * 128;
    const int nb   = blockIdx.y * 128;
    const int t    = threadIdx.x;
    const int w    = t >> 6;
    const int lane = t & 63;
    const int wm   = (w >> 1) * 64;
    const int wn   = (w & 1) * 64;
    const int lm   = lane & 15;
    const int quad = lane >> 4;

    const float*          Af = (const float*)Ap;
    const unsigned short* Ab = (const unsigned short*)Ap;

    f32x4 acc[4][4] = {};

    for (int k0 = 0; k0 < DIM; k0 += 32) {
        const int kq = k0 + quad * 8;
        short8 bfrag[4];
#pragma unroll
        for (int j = 0; j < 4; ++j) {
            const int nrow = nb + wn + j * 16 + lm;
            bfrag[j] = *(const short8*)(Wb + (size_t)nrow * DIM + kq);
        }
#pragma unroll
        for (int i = 0; i < 4; ++i) {
            const int arow = mb + wm + i * 16 + lm;
            short8 afrag;
            if constexpr (AF32) {
                const float* ap = Af + (size_t)arow * DIM + kq;
                f32x4 lo = *(const f32x4*)ap;
                f32x4 hi = *(const f32x4*)(ap + 4);
                u32x4 p;
                p[0] = pack2_rh(lo[0], lo[1]);
                p[1] = pack2_rh(lo[2], lo[3]);
                p[2] = pack2_rh(hi[0], hi[1]);
                p[3] = pack2_rh(hi[2], hi[3]);
                afrag = __builtin_bit_cast(short8, p);
            } else {
                afrag = *(const short8*)(Ab + (size_t)arow * DIM + kq);
            }
#pragma unroll
            for (int j = 0; j < 4; ++j)
                acc[i][j] = __builtin_amdgcn_mfma_f32_16x16x32_bf16(afrag, bfrag[j],
                                                                    acc[i][j], 0, 0, 0);
        }
    }

    // epilogue: C/D layout col = lane&15, row = quad*4 + reg
#pragma unroll
    for (int i = 0; i < 4; ++i) {
        const int rowbase = mb + wm + i * 16 + quad * 4;
#pragma unroll
        for (int r = 0; r < 4; ++r) {
            const int row = rowbase + r;
            int mz = 0;
            if constexpr (ACT == 2) mz = mask[row];
#pragma unroll
            for (int j = 0; j < 4; ++j) {
                const int col = nb + wn + j * 16 + lm;
                float v = acc[i][j][r] + bias[col];
                if constexpr (ACT >= 1) v = v > 0.f ? v : 0.f;
                if constexpr (ACT == 2) { if (mz) v = 0.f; }
                if constexpr (OUTF32)
                    ((float*)Cp)[(size_t)row * DIM + col] = v;
                else
                    ((unsigned short*)Cp)[(size_t)row * DIM + col] = bf16_rne(v);
            }
        }
    }
}

// ---- kv reduction: kvT[b,h,e,d] = sum_n k[b,n,h,d] * v[b,n,h,e] ----------
// also ksum[b,h,d] = sum_n k[b,n,h,d].  k is bf16 (ws), v is fp32 (d_out).
__global__ __launch_bounds__(256) void kv_kernel(const unsigned short* __restrict__ kb,
                                                 const float* __restrict__ v,
                                                 float* __restrict__ kvT,
                                                 float* __restrict__ ksum) {
    const int bh = blockIdx.x;            // 0..63
    const int bb = bh >> 4, h = bh & 15;
    const int t  = threadIdx.x;
    const int d  = t & 63;
    const int e0 = (t >> 6) * 16;
    const int n0 = blockIdx.y * (NSEQ / 16);   // 256-row chunk

    float acc[16] = {};
    float ks = 0.f;
    for (int n = n0; n < n0 + NSEQ / 16; ++n) {
        const size_t row  = (size_t)bb * NSEQ + n;
        const size_t base = row * DIM + h * HD;
        float kval = bf16_to_f32(kb[base + d]);
        const f32x4* vp = (const f32x4*)(v + base + e0);
        f32x4 v0 = vp[0], v1 = vp[1], v2 = vp[2], v3 = vp[3];
#pragma unroll
        for (int j = 0; j < 4; ++j) acc[j]      += kval * v0[j];
#pragma unroll
        for (int j = 0; j < 4; ++j) acc[4 + j]  += kval * v1[j];
#pragma unroll
        for (int j = 0; j < 4; ++j) acc[8 + j]  += kval * v2[j];
#pragma unroll
        for (int j = 0; j < 4; ++j) acc[12 + j] += kval * v3[j];
        ks += kval;
    }
#pragma unroll
    for (int j = 0; j < 16; ++j)
        atomicAdd(kvT + ((size_t)bh * HD + e0 + j) * HD + d, acc[j]);
    if (e0 == 0) atomicAdd(ksum + bh * HD + d, ks);
}

// ---- kvT fp32 -> bf16 ----------------------------------------------------
__global__ __launch_bounds__(256) void kvcvt_kernel(const float* __restrict__ src,
                                                    unsigned short* __restrict__ dst) {
    int i = blockIdx.x * blockDim.x + threadIdx.x;   // 65536 threads, 4 elems each
    f32x4 v = ((const f32x4*)src)[i];
    u16x4 o;
    o[0] = bf16_rne(v[0]); o[1] = bf16_rne(v[1]);
    o[2] = bf16_rne(v[2]); o[3] = bf16_rne(v[3]);
    ((u16x4*)dst)[i] = o;
}

// ---- denominators: den[row,h] = 1/(q[row,h,:]·ksum[b,h,:] + 1e-6) --------
__global__ __launch_bounds__(256) void den_kernel(const unsigned short* __restrict__ qb,
                                                  const float* __restrict__ ksum,
                                                  float* __restrict__ den) {
    const int idx = blockIdx.x * blockDim.x + threadIdx.x;  // 0..262143
    const int row = idx >> 4, h = idx & 15;
    const int bb  = row >> 12;
    const unsigned short* qp = qb + (size_t)row * DIM + h * HD;
    const float* kp = ksum + ((size_t)bb * NH + h) * HD;
    float s = 0.f;
#pragma unroll
    for (int d0 = 0; d0 < HD; d0 += 8) {
        short8 qv = *(const short8*)(qp + d0);
        f32x4 k0 = *(const f32x4*)(kp + d0);
        f32x4 k1 = *(const f32x4*)(kp + d0 + 4);
        s += bf16_to_f32((unsigned short)qv[0]) * k0[0];
        s += bf16_to_f32((unsigned short)qv[1]) * k0[1];
        s += bf16_to_f32((unsigned short)qv[2]) * k0[2];
        s += bf16_to_f32((unsigned short)qv[3]) * k0[3];
        s += bf16_to_f32((unsigned short)qv[4]) * k1[0];
        s += bf16_to_f32((unsigned short)qv[5]) * k1[1];
        s += bf16_to_f32((unsigned short)qv[6]) * k1[2];
        s += bf16_to_f32((unsigned short)qv[7]) * k1[3];
    }
    den[idx] = 1.f / (s + 1e-6f);
}

// ---- attention apply: attn[row, h*64+e] = den * sum_d q[row,h,d]*kv[d,e] -
// MFMA K=64: A = q rows (bf16), B[k=d][n=e] = kvT_b16[e][d] (contiguous in d)
__global__ __launch_bounds__(256) void attnout_kernel(const unsigned short* __restrict__ qb,
                                                      const unsigned short* __restrict__ kvTb,
                                                      const float* __restrict__ den,
                                                      unsigned short* __restrict__ attn) {
    const int n0   = blockIdx.x * 16;        // 16 rows per block
    const int bb   = n0 >> 12;
    const int t    = threadIdx.x;
    const int w    = t >> 6;
    const int lane = t & 63;
    const int lm   = lane & 15;
    const int quad = lane >> 4;

    for (int hh = 0; hh < 4; ++hh) {
        const int h  = w * 4 + hh;
        const int bh = bb * NH + h;
        const unsigned short* qp = qb + (size_t)(n0 + lm) * DIM + h * HD + quad * 8;
        short8 a0 = *(const short8*)qp;
        short8 a1 = *(const short8*)(qp + 32);

        f32x4 accs[4];
#pragma unroll
        for (int j = 0; j < 4; ++j) {
            const unsigned short* bp = kvTb + ((size_t)bh * HD + j * 16 + lm) * HD + quad * 8;
            short8 b0 = *(const short8*)bp;
            short8 b1 = *(const short8*)(bp + 32);
            f32x4 c = {};
            c = __builtin_amdgcn_mfma_f32_16x16x32_bf16(a0, b0, c, 0, 0, 0);
            c = __builtin_amdgcn_mfma_f32_16x16x32_bf16(a1, b1, c, 0, 0, 0);
            accs[j] = c;
        }
        float dv[4];
#pragma unroll
        for (int r = 0; r < 4; ++r)
            dv[r] = den[(size_t)(n0 + quad * 4 + r) * NH + h];
#pragma unroll
        for (int j = 0; j < 4; ++j)
#pragma unroll
            for (int r = 0; r < 4; ++r) {
                const int row = n0 + quad * 4 + r;
                attn[(size_t)row * DIM + h * HD + j * 16 + lm] = bf16_rne(accs[j][r] * dv[r]);
            }
    }
}

// ---- host ----------------------------------------------------------------
extern "C" void kernel_launch(void* const* d_in, const int* in_sizes, int n_in,
                              void* d_out, int out_size, void* d_ws, size_t ws_size,
                              hipStream_t stream) {
    const float* query = (const float*)d_in[0];
    const float* key   = (const float*)d_in[1];
    const float* value = (const float*)d_in[2];
    const float* Wq    = (const float*)d_in[3];
    const float* bq    = (const float*)d_in[4];
    const float* Wk    = (const float*)d_in[5];
    const float* bk    = (const float*)d_in[6];
    const float* Wv    = (const float*)d_in[7];
    const float* bv    = (const float*)d_in[8];
    const float* Wo    = (const float*)d_in[9];
    const float* bo    = (const float*)d_in[10];
    const int*   mask  = (const int*)d_in[11];
    float* out = (float*)d_out;
    char*  ws  = (char*)d_ws;
    const size_t MB = 1024ull * 1024ull;

    // ws layout (76 MB total):
    unsigned short* Wqb  = (unsigned short*)(ws + 0 * MB);
    unsigned short* Wkb  = (unsigned short*)(ws + 2 * MB);
    unsigned short* Wvb  = (unsigned short*)(ws + 4 * MB);
    unsigned short* Wob  = (unsigned short*)(ws + 6 * MB);
    unsigned short* qb   = (unsigned short*)(ws + 8 * MB);    // 32 MB bf16
    unsigned short* kb   = (unsigned short*)(ws + 40 * MB);   // 32 MB bf16 (reused as attn)
    float*          kvT  = (float*)(ws + 72 * MB);            // 1 MB
    float*          ksum = (float*)(ws + 73 * MB);            // 16 KB
    unsigned short* kvTb = (unsigned short*)(ws + 74 * MB);   // 0.5 MB
    float*          den  = (float*)(ws + 75 * MB);            // 1 MB
    unsigned short* attn = kb;                                // reuse after kv_kernel

    // weights -> bf16
    cvt_kernel<<<1024, 256, 0, stream>>>(Wq, Wqb, 262144);
    cvt_kernel<<<1024, 256, 0, stream>>>(Wk, Wkb, 262144);
    cvt_kernel<<<1024, 256, 0, stream>>>(Wv, Wvb, 262144);
    cvt_kernel<<<1024, 256, 0, stream>>>(Wo, Wob, 262144);

    dim3 g(MROWS / 128, DIM / 128);
    // q = relu(query@Wq^T + bq) -> bf16 ws
    gemm_kernel<1, true, false><<<g, 256, 0, stream>>>(query, Wqb, bq, qb, nullptr);
    // k = mask(relu(key@Wk^T + bk)) -> bf16 ws
    gemm_kernel<2, true, false><<<g, 256, 0, stream>>>(key, Wkb, bk, kb, mask);
    // v = value@Wv^T + bv -> fp32 in d_out (scratch until final GEMM)
    gemm_kernel<0, true, true><<<g, 256, 0, stream>>>(value, Wvb, bv, out, nullptr);

    // zero kvT + ksum accumulators
    hipMemsetAsync(ws + 72 * MB, 0, MB + 64 * 1024, stream);
    kv_kernel<<<dim3(64, 16), 256, 0, stream>>>(kb, out, kvT, ksum);
    kvcvt_kernel<<<256, 256, 0, stream>>>(kvT, kvTb);
    den_kernel<<<1024, 256, 0, stream>>>(qb, ksum, den);
    attnout_kernel<<<1024, 256, 0, stream>>>(qb, kvTb, den, attn);

    // out = attn@Wo^T + bo -> fp32 d_out
    gemm_kernel<0, false, true><<<g, 256, 0, stream>>>(attn, Wob, bo, out, nullptr);
}

// Round 2
// 564.352 us; speedup vs baseline: 1.8633x; 1.8633x over previous
//
#include <hip/hip_runtime.h>
#include <hip/hip_bf16.h>
#include <stdint.h>

#define DIM   1024
#define NSEQ  4096
#define NBAT  4
#define NH    16
#define HD    64
#define MROWS (NBAT*NSEQ)   // 16384

typedef __attribute__((ext_vector_type(8))) short  short8;
typedef __attribute__((ext_vector_type(4))) float  f32x4;
typedef __attribute__((ext_vector_type(4))) unsigned int  u32x4;
typedef __attribute__((ext_vector_type(4))) unsigned short u16x4;

// ---- helpers -------------------------------------------------------------
__device__ inline unsigned short bf16_rne(float x) {
    unsigned u = __builtin_bit_cast(unsigned, x);
    u += 0x7FFFu + ((u >> 16) & 1u);
    return (unsigned short)(u >> 16);
}
__device__ inline float bf16_to_f32(unsigned short h) {
    return __builtin_bit_cast(float, ((unsigned)h) << 16);
}
// async global->LDS, 16 bytes per lane. LDS dest must be wave-uniform base
// + lane*16 (m104/m108) — our staging layout satisfies this by construction.
__device__ inline void gld16(const unsigned short* g, unsigned short* l) {
    __builtin_amdgcn_global_load_lds(
        (const __attribute__((address_space(1))) unsigned int*)g,
        (__attribute__((address_space(3))) unsigned int*)l,
        16, 0, 0);
}

// ---- fp32 -> bf16 convert ------------------------------------------------
__global__ __launch_bounds__(256) void cvt_kernel(const float* __restrict__ src,
                                                  unsigned short* __restrict__ dst,
                                                  int n4) {
    int i = blockIdx.x * blockDim.x + threadIdx.x;
    if (i >= n4) return;
    f32x4 v = ((const f32x4*)src)[i];
    u16x4 o;
    o[0] = bf16_rne(v[0]); o[1] = bf16_rne(v[1]);
    o[2] = bf16_rne(v[2]); o[3] = bf16_rne(v[3]);
    ((u16x4*)dst)[i] = o;
}

// ---- main GEMM (m97 structure): C[M,DIM] = act(A @ W^T + bias) -----------
// A bf16 row-major [M,DIM]; W bf16 row-major [DIM,DIM] (row n holds W[n,:]).
// 128x128 block tile, BK=32, 4 waves each 64x64, global_load_lds staging.
// ACT: 0=none, 1=relu, 2=relu+zero masked rows. OUTF32: fp32 else bf16 out.
template<int ACT, bool OUTF32>
__global__ __launch_bounds__(256) void gemm_kernel(const unsigned short* __restrict__ Ab,
                                                   const unsigned short* __restrict__ Wb,
                                                   const float* __restrict__ bias,
                                                   void* __restrict__ Cp,
                                                   const int* __restrict__ mask) {
    __shared__ unsigned short As[128 * 32];
    __shared__ unsigned short Bs[128 * 32];

    const int mb   = blockIdx.x * 128;
    const int nb   = blockIdx.y * 128;
    const int t    = threadIdx.x;
    const int w    = t >> 6;
    const int lane = t & 63;
    const int wm   = (w >> 1) * 64;
    const int wn   = (w & 1) * 64;
    const int lm   = lane & 15;
    const int quad = lane >> 4;

    // staging coords: thread t covers row r0 (+64 per chunk), k-slice kidx
    const int r0   = t >> 2;          // 0..63
    const int kidx = (t & 3) * 8;     // 0,8,16,24
    const unsigned short* a0 = Ab + (size_t)(mb + r0) * DIM + kidx;
    const unsigned short* b0 = Wb + (size_t)(nb + r0) * DIM + kidx;

    f32x4 acc[4][4] = {};

    for (int k0 = 0; k0 < DIM; k0 += 32) {
        __syncthreads();   // previous iter's LDS reads done
        gld16(a0 + k0,                 As + t * 8);
        gld16(a0 + k0 + (size_t)64 * DIM, As + 2048 + t * 8);
        gld16(b0 + k0,                 Bs + t * 8);
        gld16(b0 + k0 + (size_t)64 * DIM, Bs + 2048 + t * 8);
        __syncthreads();   // staging complete (vmcnt drained before barrier)

        short8 bfrag[4];
#pragma unroll
        for (int j = 0; j < 4; ++j)
            bfrag[j] = *(const short8*)(Bs + (wn + j * 16 + lm) * 32 + quad * 8);
#pragma unroll
        for (int i = 0; i < 4; ++i) {
            short8 afrag = *(const short8*)(As + (wm + i * 16 + lm) * 32 + quad * 8);
#pragma unroll
            for (int j = 0; j < 4; ++j)
                acc[i][j] = __builtin_amdgcn_mfma_f32_16x16x32_bf16(afrag, bfrag[j],
                                                                    acc[i][j], 0, 0, 0);
        }
    }

    // epilogue: C/D layout col = lane&15, row = quad*4 + reg (m89/m91)
#pragma unroll
    for (int i = 0; i < 4; ++i) {
        const int rowbase = mb + wm + i * 16 + quad * 4;
#pragma unroll
        for (int r = 0; r < 4; ++r) {
            const int row = rowbase + r;
            int mz = 0;
            if constexpr (ACT == 2) mz = mask[row];
#pragma unroll
            for (int j = 0; j < 4; ++j) {
                const int col = nb + wn + j * 16 + lm;
                float v = acc[i][j][r] + bias[col];
                if constexpr (ACT >= 1) v = v > 0.f ? v : 0.f;
                if constexpr (ACT == 2) { if (mz) v = 0.f; }
                if constexpr (OUTF32)
                    ((float*)Cp)[(size_t)row * DIM + col] = v;
                else
                    ((unsigned short*)Cp)[(size_t)row * DIM + col] = bf16_rne(v);
            }
        }
    }
}

// ---- kv reduction: kvT[b,h,e,d] = sum_n k[b,n,h,d]*v[b,n,h,e]; ksum too --
// k and v both bf16.
__global__ __launch_bounds__(256) void kv_kernel(const unsigned short* __restrict__ kb,
                                                 const unsigned short* __restrict__ vb,
                                                 float* __restrict__ kvT,
                                                 float* __restrict__ ksum) {
    const int bh = blockIdx.x;            // 0..63
    const int bb = bh >> 4, h = bh & 15;
    const int t  = threadIdx.x;
    const int d  = t & 63;
    const int e0 = (t >> 6) * 16;
    const int n0 = blockIdx.y * (NSEQ / 16);   // 256-row chunk

    float acc[16] = {};
    float ks = 0.f;
    for (int n = n0; n < n0 + NSEQ / 16; ++n) {
        const size_t base = ((size_t)bb * NSEQ + n) * DIM + h * HD;
        float kval = bf16_to_f32(kb[base + d]);
        short8 v0 = *(const short8*)(vb + base + e0);
        short8 v1 = *(const short8*)(vb + base + e0 + 8);
#pragma unroll
        for (int j = 0; j < 8; ++j) acc[j]     += kval * bf16_to_f32((unsigned short)v0[j]);
#pragma unroll
        for (int j = 0; j < 8; ++j) acc[8 + j] += kval * bf16_to_f32((unsigned short)v1[j]);
        ks += kval;
    }
#pragma unroll
    for (int j = 0; j < 16; ++j)
        atomicAdd(kvT + ((size_t)bh * HD + e0 + j) * HD + d, acc[j]);
    if (e0 == 0) atomicAdd(ksum + bh * HD + d, ks);
}

// ---- kvT fp32 -> bf16 ----------------------------------------------------
__global__ __launch_bounds__(256) void kvcvt_kernel(const float* __restrict__ src,
                                                    unsigned short* __restrict__ dst) {
    int i = blockIdx.x * blockDim.x + threadIdx.x;
    f32x4 v = ((const f32x4*)src)[i];
    u16x4 o;
    o[0] = bf16_rne(v[0]); o[1] = bf16_rne(v[1]);
    o[2] = bf16_rne(v[2]); o[3] = bf16_rne(v[3]);
    ((u16x4*)dst)[i] = o;
}

// ---- denominators: den[row,h] = 1/(q[row,h,:]·ksum[b,h,:] + 1e-6) --------
__global__ __launch_bounds__(256) void den_kernel(const unsigned short* __restrict__ qb,
                                                  const float* __restrict__ ksum,
                                                  float* __restrict__ den) {
    const int idx = blockIdx.x * blockDim.x + threadIdx.x;  // row*16+h
    const int row = idx >> 4, h = idx & 15;
    const int bb  = row >> 12;
    const unsigned short* qp = qb + (size_t)row * DIM + h * HD;
    const float* kp = ksum + ((size_t)bb * NH + h) * HD;
    float s = 0.f;
#pragma unroll
    for (int d0 = 0; d0 < HD; d0 += 8) {
        short8 qv = *(const short8*)(qp + d0);
        f32x4 k0 = *(const f32x4*)(kp + d0);
        f32x4 k1 = *(const f32x4*)(kp + d0 + 4);
        s += bf16_to_f32((unsigned short)qv[0]) * k0[0];
        s += bf16_to_f32((unsigned short)qv[1]) * k0[1];
        s += bf16_to_f32((unsigned short)qv[2]) * k0[2];
        s += bf16_to_f32((unsigned short)qv[3]) * k0[3];
        s += bf16_to_f32((unsigned short)qv[4]) * k1[0];
        s += bf16_to_f32((unsigned short)qv[5]) * k1[1];
        s += bf16_to_f32((unsigned short)qv[6]) * k1[2];
        s += bf16_to_f32((unsigned short)qv[7]) * k1[3];
    }
    den[idx] = 1.f / (s + 1e-6f);
}

// ---- attention apply: attn[row,h*64+e] = den * sum_d q[row,h,d]*kvT[e,d] -
__global__ __launch_bounds__(256) void attnout_kernel(const unsigned short* __restrict__ qb,
                                                      const unsigned short* __restrict__ kvTb,
                                                      const float* __restrict__ den,
                                                      unsigned short* __restrict__ attn) {
    const int n0   = blockIdx.x * 16;
    const int bb   = n0 >> 12;
    const int t    = threadIdx.x;
    const int w    = t >> 6;
    const int lane = t & 63;
    const int lm   = lane & 15;
    const int quad = lane >> 4;

    for (int hh = 0; hh < 4; ++hh) {
        const int h  = w * 4 + hh;
        const int bh = bb * NH + h;
        const unsigned short* qp = qb + (size_t)(n0 + lm) * DIM + h * HD + quad * 8;
        short8 a0 = *(const short8*)qp;
        short8 a1 = *(const short8*)(qp + 32);

        f32x4 accs[4];
#pragma unroll
        for (int j = 0; j < 4; ++j) {
            const unsigned short* bp = kvTb + ((size_t)bh * HD + j * 16 + lm) * HD + quad * 8;
            short8 b0 = *(const short8*)bp;
            short8 b1 = *(const short8*)(bp + 32);
            f32x4 c = {};
            c = __builtin_amdgcn_mfma_f32_16x16x32_bf16(a0, b0, c, 0, 0, 0);
            c = __builtin_amdgcn_mfma_f32_16x16x32_bf16(a1, b1, c, 0, 0, 0);
            accs[j] = c;
        }
        float dv[4];
#pragma unroll
        for (int r = 0; r < 4; ++r)
            dv[r] = den[(size_t)(n0 + quad * 4 + r) * NH + h];
#pragma unroll
        for (int j = 0; j < 4; ++j)
#pragma unroll
            for (int r = 0; r < 4; ++r) {
                const int row = n0 + quad * 4 + r;
                attn[(size_t)row * DIM + h * HD + j * 16 + lm] = bf16_rne(accs[j][r] * dv[r]);
            }
    }
}

// ---- host ----------------------------------------------------------------
extern "C" void kernel_launch(void* const* d_in, const int* in_sizes, int n_in,
                              void* d_out, int out_size, void* d_ws, size_t ws_size,
                              hipStream_t stream) {
    const float* query = (const float*)d_in[0];
    const float* key   = (const float*)d_in[1];
    const float* value = (const float*)d_in[2];
    const float* Wq    = (const float*)d_in[3];
    const float* bq    = (const float*)d_in[4];
    const float* Wk    = (const float*)d_in[5];
    const float* bk    = (const float*)d_in[6];
    const float* Wv    = (const float*)d_in[7];
    const float* bv    = (const float*)d_in[8];
    const float* Wo    = (const float*)d_in[9];
    const float* bo    = (const float*)d_in[10];
    const int*   mask  = (const int*)d_in[11];
    float* out = (float*)d_out;
    char*  ws  = (char*)d_ws;
    const size_t MB = 1024ull * 1024ull;

    // ws layout (76 MB, same budget as R1 which fit):
    unsigned short* Wqb  = (unsigned short*)(ws + 0 * MB);
    unsigned short* Wkb  = (unsigned short*)(ws + 2 * MB);
    unsigned short* Wvb  = (unsigned short*)(ws + 4 * MB);
    unsigned short* Wob  = (unsigned short*)(ws + 6 * MB);
    unsigned short* qb   = (unsigned short*)(ws + 8 * MB);    // 32 MB bf16
    unsigned short* kb   = (unsigned short*)(ws + 40 * MB);   // 32 MB (reused as attn)
    float*          kvT  = (float*)(ws + 72 * MB);            // 1 MB
    float*          ksum = (float*)(ws + 73 * MB);            // 16 KB
    unsigned short* kvTb = (unsigned short*)(ws + 74 * MB);   // 0.5 MB
    float*          den  = (float*)(ws + 75 * MB);            // 1 MB
    unsigned short* attn = kb;

    // d_out (64 MB fp32) doubles as scratch until the final GEMM:
    unsigned short* vb = (unsigned short*)d_out;              // v bf16, 32 MB
    unsigned short* xb = (unsigned short*)((char*)d_out + 32 * MB); // A-cvt staging, 32 MB

    // weights -> bf16
    cvt_kernel<<<1024, 256, 0, stream>>>(Wq, Wqb, 262144);
    cvt_kernel<<<1024, 256, 0, stream>>>(Wk, Wkb, 262144);
    cvt_kernel<<<1024, 256, 0, stream>>>(Wv, Wvb, 262144);
    cvt_kernel<<<1024, 256, 0, stream>>>(Wo, Wob, 262144);

    dim3 g(MROWS / 128, DIM / 128);
    // q = relu(query@Wq^T + bq)
    cvt_kernel<<<16384, 256, 0, stream>>>(query, xb, 4194304);
    gemm_kernel<1, false><<<g, 256, 0, stream>>>(xb, Wqb, bq, qb, nullptr);
    // k = mask(relu(key@Wk^T + bk))
    cvt_kernel<<<16384, 256, 0, stream>>>(key, xb, 4194304);
    gemm_kernel<2, false><<<g, 256, 0, stream>>>(xb, Wkb, bk, kb, mask);
    // v = value@Wv^T + bv  (bf16, into d_out first half)
    cvt_kernel<<<16384, 256, 0, stream>>>(value, xb, 4194304);
    gemm_kernel<0, false><<<g, 256, 0, stream>>>(xb, Wvb, bv, vb, nullptr);

    hipMemsetAsync(ws + 72 * MB, 0, MB + 64 * 1024, stream);
    kv_kernel<<<dim3(64, 16), 256, 0, stream>>>(kb, vb, kvT, ksum);
    kvcvt_kernel<<<256, 256, 0, stream>>>(kvT, kvTb);
    den_kernel<<<1024, 256, 0, stream>>>(qb, ksum, den);
    attnout_kernel<<<1024, 256, 0, stream>>>(qb, kvTb, den, attn);

    // out = attn@Wo^T + bo -> fp32 d_out (overwrites vb/xb scratch)
    gemm_kernel<0, true><<<g, 256, 0, stream>>>(attn, Wob, bo, out, nullptr);
}

// Round 4
// 543.333 us; speedup vs baseline: 1.9354x; 1.0387x over previous
//
#include <hip/hip_runtime.h>
#include <hip/hip_bf16.h>
#include <stdint.h>

#define DIM   1024
#define NSEQ  4096
#define NBAT  4
#define NH    16
#define HD    64
#define MROWS (NBAT*NSEQ)   // 16384

typedef __attribute__((ext_vector_type(8))) short  short8;
typedef __attribute__((ext_vector_type(4))) float  f32x4;
typedef __attribute__((ext_vector_type(4))) unsigned int  u32x4;
typedef __attribute__((ext_vector_type(4))) unsigned short u16x4;

// ---- helpers -------------------------------------------------------------
__device__ inline unsigned short bf16_rne(float x) {
    unsigned u = __builtin_bit_cast(unsigned, x);
    u += 0x7FFFu + ((u >> 16) & 1u);
    return (unsigned short)(u >> 16);
}
__device__ inline float bf16_to_f32(unsigned short h) {
    return __builtin_bit_cast(float, ((unsigned)h) << 16);
}
__device__ inline unsigned pack2_rh(float a, float b) {
    unsigned ua = __builtin_bit_cast(unsigned, a) + 0x8000u;
    unsigned ub = __builtin_bit_cast(unsigned, b) + 0x8000u;
    return __builtin_amdgcn_perm(ub, ua, 0x07060302u);  // a->lo16, b->hi16
}
__device__ inline void gld16(const unsigned short* g, unsigned short* l) {
    __builtin_amdgcn_global_load_lds(
        (const __attribute__((address_space(1))) unsigned int*)g,
        (__attribute__((address_space(3))) unsigned int*)l,
        16, 0, 0);
}

// ---- all 4 weights fp32->bf16, one launch --------------------------------
__global__ __launch_bounds__(256) void wcvt_kernel(const float* __restrict__ s0, const float* __restrict__ s1,
                                                   const float* __restrict__ s2, const float* __restrict__ s3,
                                                   unsigned short* __restrict__ d0, unsigned short* __restrict__ d1,
                                                   unsigned short* __restrict__ d2, unsigned short* __restrict__ d3) {
    int i = blockIdx.x * 256 + threadIdx.x;     // 0..1048575, 4 f32 each
    int w = i >> 18, j = i & 262143;
    const float* s = (w == 0) ? s0 : (w == 1) ? s1 : (w == 2) ? s2 : s3;
    unsigned short* d = (w == 0) ? d0 : (w == 1) ? d1 : (w == 2) ? d2 : d3;
    f32x4 v = ((const f32x4*)s)[j];
    u16x4 o;
    o[0] = bf16_rne(v[0]); o[1] = bf16_rne(v[1]);
    o[2] = bf16_rne(v[2]); o[3] = bf16_rne(v[3]);
    ((u16x4*)d)[j] = o;
}

// ---- QKV GEMM: C_bf16[M,DIM] = act(A_f32 @ W^T + bias) -------------------
// A fp32 via register path (load+pack+ds_write); W bf16 via async gld16.
// ACT: 0=none, 1=relu, 2=relu+zero masked rows.
template<int ACT>
__global__ __launch_bounds__(256) void gemm_a32_kernel(const float* __restrict__ Af,
                                                       const unsigned short* __restrict__ Wb,
                                                       const float* __restrict__ bias,
                                                       unsigned short* __restrict__ Cp,
                                                       const int* __restrict__ mask) {
    __shared__ unsigned short As[128 * 32];
    __shared__ unsigned short Bs[128 * 32];

    const int mb   = blockIdx.x * 128;
    const int nb   = blockIdx.y * 128;
    const int t    = threadIdx.x;
    const int w    = t >> 6;
    const int lane = t & 63;
    const int wm   = (w >> 1) * 64;
    const int wn   = (w & 1) * 64;
    const int lm   = lane & 15;
    const int quad = lane >> 4;

    const int r0   = t >> 2;          // 0..63
    const int kidx = (t & 3) * 8;     // 0,8,16,24
    const float*          a0 = Af + (size_t)(mb + r0) * DIM + kidx;
    const unsigned short* b0 = Wb + (size_t)(nb + r0) * DIM + kidx;

    f32x4 acc[4][4] = {};

    for (int k0 = 0; k0 < DIM; k0 += 32) {
        // prefetch A fp32 (independent of LDS, can issue early)
        f32x4 x0 = *(const f32x4*)(a0 + k0);
        f32x4 x1 = *(const f32x4*)(a0 + k0 + 4);
        f32x4 y0 = *(const f32x4*)(a0 + k0 + (size_t)64 * DIM);
        f32x4 y1 = *(const f32x4*)(a0 + k0 + (size_t)64 * DIM + 4);
        __syncthreads();   // prev iter's LDS reads done
        gld16(b0 + k0,                    Bs + t * 8);
        gld16(b0 + k0 + (size_t)64 * DIM, Bs + 2048 + t * 8);
        u32x4 p, q;
        p[0] = pack2_rh(x0[0], x0[1]); p[1] = pack2_rh(x0[2], x0[3]);
        p[2] = pack2_rh(x1[0], x1[1]); p[3] = pack2_rh(x1[2], x1[3]);
        q[0] = pack2_rh(y0[0], y0[1]); q[1] = pack2_rh(y0[2], y0[3]);
        q[2] = pack2_rh(y1[0], y1[1]); q[3] = pack2_rh(y1[2], y1[3]);
        *(u32x4*)(As + t * 8)        = p;
        *(u32x4*)(As + 2048 + t * 8) = q;
        __syncthreads();   // staging complete

        short8 bfrag[4];
#pragma unroll
        for (int j = 0; j < 4; ++j)
            bfrag[j] = *(const short8*)(Bs + (wn + j * 16 + lm) * 32 + quad * 8);
#pragma unroll
        for (int i = 0; i < 4; ++i) {
            short8 afrag = *(const short8*)(As + (wm + i * 16 + lm) * 32 + quad * 8);
#pragma unroll
            for (int j = 0; j < 4; ++j)
                acc[i][j] = __builtin_amdgcn_mfma_f32_16x16x32_bf16(afrag, bfrag[j],
                                                                    acc[i][j], 0, 0, 0);
        }
    }

#pragma unroll
    for (int i = 0; i < 4; ++i) {
        const int rowbase = mb + wm + i * 16 + quad * 4;
#pragma unroll
        for (int r = 0; r < 4; ++r) {
            const int row = rowbase + r;
            int mz = 0;
            if constexpr (ACT == 2) mz = mask[row];
#pragma unroll
            for (int j = 0; j < 4; ++j) {
                const int col = nb + wn + j * 16 + lm;
                float v = acc[i][j][r] + bias[col];
                if constexpr (ACT >= 1) v = v > 0.f ? v : 0.f;
                if constexpr (ACT == 2) { if (mz) v = 0.f; }
                Cp[(size_t)row * DIM + col] = bf16_rne(v);
            }
        }
    }
}

// ---- final GEMM (m97 structure, bf16 A): out_f32 = A @ W^T + bias --------
__global__ __launch_bounds__(256) void gemm_bf16_kernel(const unsigned short* __restrict__ Ab,
                                                        const unsigned short* __restrict__ Wb,
                                                        const float* __restrict__ bias,
                                                        float* __restrict__ Cp) {
    __shared__ unsigned short As[128 * 32];
    __shared__ unsigned short Bs[128 * 32];

    const int mb   = blockIdx.x * 128;
    const int nb   = blockIdx.y * 128;
    const int t    = threadIdx.x;
    const int w    = t >> 6;
    const int lane = t & 63;
    const int wm   = (w >> 1) * 64;
    const int wn   = (w & 1) * 64;
    const int lm   = lane & 15;
    const int quad = lane >> 4;

    const int r0   = t >> 2;
    const int kidx = (t & 3) * 8;
    const unsigned short* a0 = Ab + (size_t)(mb + r0) * DIM + kidx;
    const unsigned short* b0 = Wb + (size_t)(nb + r0) * DIM + kidx;

    f32x4 acc[4][4] = {};

    for (int k0 = 0; k0 < DIM; k0 += 32) {
        __syncthreads();
        gld16(a0 + k0,                    As + t * 8);
        gld16(a0 + k0 + (size_t)64 * DIM, As + 2048 + t * 8);
        gld16(b0 + k0,                    Bs + t * 8);
        gld16(b0 + k0 + (size_t)64 * DIM, Bs + 2048 + t * 8);
        __syncthreads();

        short8 bfrag[4];
#pragma unroll
        for (int j = 0; j < 4; ++j)
            bfrag[j] = *(const short8*)(Bs + (wn + j * 16 + lm) * 32 + quad * 8);
#pragma unroll
        for (int i = 0; i < 4; ++i) {
            short8 afrag = *(const short8*)(As + (wm + i * 16 + lm) * 32 + quad * 8);
#pragma unroll
            for (int j = 0; j < 4; ++j)
                acc[i][j] = __builtin_amdgcn_mfma_f32_16x16x32_bf16(afrag, bfrag[j],
                                                                    acc[i][j], 0, 0, 0);
        }
    }

#pragma unroll
    for (int i = 0; i < 4; ++i) {
        const int rowbase = mb + wm + i * 16 + quad * 4;
#pragma unroll
        for (int r = 0; r < 4; ++r) {
#pragma unroll
            for (int j = 0; j < 4; ++j) {
                const int col = nb + wn + j * 16 + lm;
                Cp[(size_t)(rowbase + r) * DIM + col] = acc[i][j][r] + bias[col];
            }
        }
    }
}

// ---- kv via MFMA: per (bh, chunk) compute partial kvT[e][d] over 512 rows -
// kT/vT staged transposed in LDS. rowoff: pitch 40 + alternating 8-offset per
// 8-row group. No overlap (within group delta 40>32; at crossings 40-8=32 or
// 40+8=48), rows stay 16B-aligned for ds_read_b128.
// [R3 BUG FIXED: previous ((d>>3)&3)*8 wrapped 24->0 at d=31->32, delta 16<32
//  -> rows 31/32 overlapped 16 elements -> absmax 6.5e-3.]
__device__ inline int rowoff(int d) { return d * 40 + ((d >> 3) & 1) * 8; }

__global__ __launch_bounds__(256) void kvmfma_kernel(const unsigned short* __restrict__ kb,
                                                     const unsigned short* __restrict__ vb,
                                                     float* __restrict__ kvT8,
                                                     float* __restrict__ ksum8) {
    __shared__ unsigned short kT[2624];
    __shared__ unsigned short vT[2624];
    __shared__ float ksl[64];

    const int bh    = blockIdx.x;            // 0..63
    const int bb    = bh >> 4, h = bh & 15;
    const int chunk = blockIdx.y;            // 0..7, 512 rows each
    const int t     = threadIdx.x;
    const int w     = t >> 6;
    const int lane  = t & 63;
    const int lm    = lane & 15;
    const int quad  = lane >> 4;
    const int sn    = t >> 3;                // staging row 0..31
    const int d0    = (t & 7) * 8;           // staging d offset

    const size_t gbase = ((size_t)bb * NSEQ + (size_t)chunk * 512) * DIM + h * HD;
    const unsigned short* kp = kb + gbase + (size_t)sn * DIM + d0;
    const unsigned short* vp = vb + gbase + (size_t)sn * DIM + d0;

    if (t < 64) ksl[t] = 0.f;

    float ks[8] = {};
    f32x4 acc[4] = {};

    for (int n0 = 0; n0 < 512; n0 += 32) {
        short8 kx = *(const short8*)(kp + (size_t)n0 * DIM);
        short8 vx = *(const short8*)(vp + (size_t)n0 * DIM);
        __syncthreads();
#pragma unroll
        for (int j = 0; j < 8; ++j) {
            const int ro = rowoff(d0 + j);
            kT[ro + sn] = (unsigned short)kx[j];
            vT[ro + sn] = (unsigned short)vx[j];
            ks[j] += bf16_to_f32((unsigned short)kx[j]);
        }
        __syncthreads();
        // A[m=e][k=n] = vT[e][n]; wave w covers e-strip w*16..w*16+16
        short8 afrag = *(const short8*)(vT + rowoff(w * 16 + lm) + quad * 8);
#pragma unroll
        for (int jd = 0; jd < 4; ++jd) {
            short8 bfrag = *(const short8*)(kT + rowoff(jd * 16 + lm) + quad * 8);
            acc[jd] = __builtin_amdgcn_mfma_f32_16x16x32_bf16(afrag, bfrag, acc[jd], 0, 0, 0);
        }
    }

    // epilogue: C[e = w*16 + quad*4 + r][d = jd*16 + lm]
    const size_t obase = ((size_t)chunk * 64 + bh) * 4096;
#pragma unroll
    for (int jd = 0; jd < 4; ++jd)
#pragma unroll
        for (int r = 0; r < 4; ++r) {
            const int e = w * 16 + quad * 4 + r;
            const int d = jd * 16 + lm;
            kvT8[obase + e * 64 + d] = acc[jd][r];
        }

    __syncthreads();
#pragma unroll
    for (int j = 0; j < 8; ++j) atomicAdd(&ksl[d0 + j], ks[j]);
    __syncthreads();
    if (t < 64) ksum8[((size_t)chunk * 64 + bh) * 64 + t] = ksl[t];
}

// ---- reduce 8 chunk-slices -> kvTb bf16 + ksum fp32 ----------------------
__global__ __launch_bounds__(256) void kvsum_kernel(const float* __restrict__ kvT8,
                                                    const float* __restrict__ ksum8,
                                                    unsigned short* __restrict__ kvTb,
                                                    float* __restrict__ ksum) {
    int idx = blockIdx.x * 256 + threadIdx.x;
    if (idx < 262144) {
        float s = 0.f;
#pragma unroll
        for (int c = 0; c < 8; ++c) s += kvT8[(size_t)c * 262144 + idx];
        kvTb[idx] = bf16_rne(s);
    } else {
        int j = idx - 262144;   // < 4096
        float s = 0.f;
#pragma unroll
        for (int c = 0; c < 8; ++c) s += ksum8[(size_t)c * 4096 + j];
        ksum[j] = s;
    }
}

// ---- attention apply + fused denominator ---------------------------------
__global__ __launch_bounds__(256) void attnout_kernel(const unsigned short* __restrict__ qb,
                                                      const unsigned short* __restrict__ kvTb,
                                                      const float* __restrict__ ksum,
                                                      unsigned short* __restrict__ attn) {
    const int n0   = blockIdx.x * 16;
    const int bb   = n0 >> 12;
    const int t    = threadIdx.x;
    const int w    = t >> 6;
    const int lane = t & 63;
    const int lm   = lane & 15;
    const int quad = lane >> 4;

    for (int hh = 0; hh < 4; ++hh) {
        const int h  = w * 4 + hh;
        const int bh = bb * NH + h;
        const unsigned short* qp = qb + (size_t)(n0 + lm) * DIM + h * HD + quad * 8;
        short8 a0 = *(const short8*)qp;
        short8 a1 = *(const short8*)(qp + 32);

        // denominator: row lm's q · ksum (this lane holds k-slice quad*8..+8, +32)
        const float* ksp = ksum + (size_t)bh * HD + quad * 8;
        float part = 0.f;
#pragma unroll
        for (int j = 0; j < 8; ++j)
            part += bf16_to_f32((unsigned short)a0[j]) * ksp[j]
                  + bf16_to_f32((unsigned short)a1[j]) * ksp[32 + j];
        part += __shfl_xor(part, 16, 64);
        part += __shfl_xor(part, 32, 64);
        float dinv = 1.f / (part + 1e-6f);   // lane l holds row (l&15)'s value

        f32x4 accs[4];
#pragma unroll
        for (int j = 0; j < 4; ++j) {
            const unsigned short* bp = kvTb + ((size_t)bh * HD + j * 16 + lm) * HD + quad * 8;
            short8 b0 = *(const short8*)bp;
            short8 b1 = *(const short8*)(bp + 32);
            f32x4 c = {};
            c = __builtin_amdgcn_mfma_f32_16x16x32_bf16(a0, b0, c, 0, 0, 0);
            c = __builtin_amdgcn_mfma_f32_16x16x32_bf16(a1, b1, c, 0, 0, 0);
            accs[j] = c;
        }
        float dv[4];
#pragma unroll
        for (int r = 0; r < 4; ++r)
            dv[r] = __shfl(dinv, quad * 4 + r, 64);
#pragma unroll
        for (int j = 0; j < 4; ++j)
#pragma unroll
            for (int r = 0; r < 4; ++r) {
                const int row = n0 + quad * 4 + r;
                attn[(size_t)row * DIM + h * HD + j * 16 + lm] = bf16_rne(accs[j][r] * dv[r]);
            }
    }
}

// ---- host ----------------------------------------------------------------
extern "C" void kernel_launch(void* const* d_in, const int* in_sizes, int n_in,
                              void* d_out, int out_size, void* d_ws, size_t ws_size,
                              hipStream_t stream) {
    const float* query = (const float*)d_in[0];
    const float* key   = (const float*)d_in[1];
    const float* value = (const float*)d_in[2];
    const float* Wq    = (const float*)d_in[3];
    const float* bq    = (const float*)d_in[4];
    const float* Wk    = (const float*)d_in[5];
    const float* bk    = (const float*)d_in[6];
    const float* Wv    = (const float*)d_in[7];
    const float* bv    = (const float*)d_in[8];
    const float* Wo    = (const float*)d_in[9];
    const float* bo    = (const float*)d_in[10];
    const int*   mask  = (const int*)d_in[11];
    float* out = (float*)d_out;
    char*  ws  = (char*)d_ws;
    const size_t MB = 1024ull * 1024ull;

    // ws layout (74 MB):
    unsigned short* Wqb  = (unsigned short*)(ws + 0 * MB);
    unsigned short* Wkb  = (unsigned short*)(ws + 2 * MB);
    unsigned short* Wvb  = (unsigned short*)(ws + 4 * MB);
    unsigned short* Wob  = (unsigned short*)(ws + 6 * MB);
    unsigned short* qb   = (unsigned short*)(ws + 8 * MB);    // 32 MB
    unsigned short* kb   = (unsigned short*)(ws + 40 * MB);   // 32 MB (reused as attn)
    unsigned short* kvTb = (unsigned short*)(ws + 72 * MB);   // 0.5 MB
    float*          ksum = (float*)(ws + 73 * MB);            // 16 KB
    unsigned short* attn = kb;

    // d_out (64 MB) as scratch until final GEMM:
    unsigned short* vb    = (unsigned short*)d_out;                 // 32 MB bf16
    float*          kvT8  = (float*)((char*)d_out + 32 * MB);       // 8 MB
    float*          ksum8 = (float*)((char*)d_out + 40 * MB);       // 128 KB

    wcvt_kernel<<<4096, 256, 0, stream>>>(Wq, Wk, Wv, Wo, Wqb, Wkb, Wvb, Wob);

    dim3 g(MROWS / 128, DIM / 128);
    gemm_a32_kernel<1><<<g, 256, 0, stream>>>(query, Wqb, bq, qb, nullptr);
    gemm_a32_kernel<2><<<g, 256, 0, stream>>>(key,   Wkb, bk, kb, mask);
    gemm_a32_kernel<0><<<g, 256, 0, stream>>>(value, Wvb, bv, vb, nullptr);

    kvmfma_kernel<<<dim3(64, 8), 256, 0, stream>>>(kb, vb, kvT8, ksum8);
    kvsum_kernel<<<1040, 256, 0, stream>>>(kvT8, ksum8, kvTb, ksum);
    attnout_kernel<<<1024, 256, 0, stream>>>(qb, kvTb, ksum, attn);

    gemm_bf16_kernel<<<g, 256, 0, stream>>>(attn, Wob, bo, out);
}